// Round 4
// baseline (639.084 us; speedup 1.0000x reference)
//
#include <hip/hip_runtime.h>
#include <math.h>

// LieBatchNormSPD on MI355X — round 3 (resubmit: fix cvt_pkrtz return type:
// builtin returns __fp16 ext_vector(2), not _Float16; scalar-cast elements).
// vs round 2: (a) k_prep Cholesky/tri-inverse rewritten as register+shuffle
// (was LDS-RMW latency-serial, 145us single-wave). (b) Chebyshev deg 22->18 on
// tightened interval [0.396,4.196] (t=0.53), KFULL 8->5; exp deg 10->7 with
// hi-only early Horner steps. (c) packed v_cvt_pkrtz conversions. (d) ITER 8->4
// (1024 blocks -> 4 blocks/CU possible); A/B: k_center/k_scale at
// __launch_bounds__(256,4) vs k_karcher at (256,3).

#define NM 32
#define PAD 36
#define WCNT 4
#define ITER 4
#define EXP_DEG 10   // prep/bmroot VALU chains keep deg 10
#define KFULL 5

// Chebyshev log on [m-h, m+h], t=0.53, h=1.9, m=z*h, z=(t+1/t)/2
#define CH_2overH 1.0526316f
#define CH_2Z     2.4167925f
#define CH_C0     0.58358485f
#define CH_C17    2.4170800e-6f
#define CH_C18   -1.2098800e-6f
#define CH_PK16   3.8764500e-5f   // t^16
#define CH_TINV   1.8867925f      // 1/t

typedef _Float16 v8h __attribute__((ext_vector_type(8)));
typedef __fp16 pk2 __attribute__((ext_vector_type(2)));
typedef float v16f __attribute__((ext_vector_type(16)));
#define MFMA(a, b, c) __builtin_amdgcn_mfma_f32_32x32x16_f16((a), (b), (c), 0, 0, 0)

struct Frag4 { v8h h1, l1, h2, l2; };

// ---------------------------------------------------------------------------
__device__ __forceinline__ v8h pk8(const float (&v)[8])
{
  pk2 p0 = __builtin_amdgcn_cvt_pkrtz(v[0], v[1]);
  pk2 p1 = __builtin_amdgcn_cvt_pkrtz(v[2], v[3]);
  pk2 p2 = __builtin_amdgcn_cvt_pkrtz(v[4], v[5]);
  pk2 p3 = __builtin_amdgcn_cvt_pkrtz(v[6], v[7]);
  v8h r;
  r[0] = (_Float16)p0[0]; r[1] = (_Float16)p0[1];
  r[2] = (_Float16)p1[0]; r[3] = (_Float16)p1[1];
  r[4] = (_Float16)p2[0]; r[5] = (_Float16)p2[1];
  r[6] = (_Float16)p3[0]; r[7] = (_Float16)p3[1];
  return r;
}

// fp32[8] -> f16 hi (RTZ) + f16 residual lo
__device__ __forceinline__ void cvt_split(const float (&v)[8], v8h& hi, v8h& lo)
{
  hi = pk8(v);
  float r[8];
#pragma unroll
  for (int i = 0; i < 8; ++i) r[i] = v[i] - (float)hi[i];
  lo = pk8(r);
}

__device__ __forceinline__ v8h cvt_hi(const float (&v)[8]) { return pk8(v); }

__device__ __forceinline__ Frag4 split_frag(const float (&v1)[8], const float (&v2)[8])
{
  Frag4 f;
  cvt_split(v1, f.h1, f.l1);
  cvt_split(v2, f.h2, f.l2);
  return f;
}

// Full split product: acc += A*B, dropping lo*lo.
__device__ __forceinline__ v16f prodAB(const Frag4& A, const Frag4& B, v16f acc)
{
  acc = MFMA(A.h1, B.h1, acc);
  acc = MFMA(A.h2, B.h2, acc);
  acc = MFMA(A.h1, B.l1, acc);
  acc = MFMA(A.h2, B.l2, acc);
  acc = MFMA(A.l1, B.h1, acc);
  acc = MFMA(A.l2, B.h2, acc);
  return acc;
}

// Build B-frag fp32 values (column lane&31, k-ordered) from C-layout regs.
__device__ __forceinline__ void gather16(const float (&y)[16], bool lower,
                                         float (&v1)[8], float (&v2)[8])
{
  float r0[4], r1[4];
#pragma unroll
  for (int i = 0; i < 4; ++i) {
    r0[i] = __shfl_xor(lower ? y[4 + i] : y[i], 32);
    r1[i] = __shfl_xor(lower ? y[12 + i] : y[8 + i], 32);
  }
#pragma unroll
  for (int i = 0; i < 4; ++i) {
    v1[i]     = lower ? y[i]      : r0[i];
    v1[4 + i] = lower ? r0[i]     : y[4 + i];
    v2[i]     = lower ? y[8 + i]  : r1[i];
    v2[4 + i] = lower ? r1[i]     : y[12 + i];
  }
}

// Resident small-matrix fragments: rows of T (row-major 32x32 global).
__device__ __forceinline__ Frag4 load_T(const float* __restrict__ T, int l)
{
  const int c = l & 31, k0 = 8 * (l >> 5);
  float a1[8], a2[8];
  const float4 t0 = *(const float4*)(T + c * 32 + k0);
  const float4 t1 = *(const float4*)(T + c * 32 + k0 + 4);
  const float4 t2 = *(const float4*)(T + c * 32 + 16 + k0);
  const float4 t3 = *(const float4*)(T + c * 32 + 16 + k0 + 4);
  a1[0] = t0.x; a1[1] = t0.y; a1[2] = t0.z; a1[3] = t0.w;
  a1[4] = t1.x; a1[5] = t1.y; a1[6] = t1.z; a1[7] = t1.w;
  a2[0] = t2.x; a2[1] = t2.y; a2[2] = t2.z; a2[3] = t2.w;
  a2[4] = t3.x; a2[5] = t3.y; a2[6] = t3.z; a2[7] = t3.w;
  return split_frag(a1, a2);
}

// One Clenshaw step: yio <- U*yin - yio + ck*I  (hi-only when !full)
__device__ __forceinline__ void clen_step(const float (&yin)[16], float (&yio)[16],
                                          float ck, bool full, const Frag4& uf,
                                          const float (&dsel)[16], bool lower)
{
  float v1[8], v2[8];
  gather16(yin, lower, v1, v2);
  v16f acc;
#pragma unroll
  for (int g = 0; g < 16; ++g) acc[g] = fmaf(ck, dsel[g], -yio[g]);
  v8h bh1 = cvt_hi(v1), bh2 = cvt_hi(v2);
  acc = MFMA(uf.h1, bh1, acc);
  acc = MFMA(uf.h2, bh2, acc);
  if (full) {
    float r1[8], r2[8];
#pragma unroll
    for (int i = 0; i < 8; ++i) {
      r1[i] = v1[i] - (float)bh1[i];
      r2[i] = v2[i] - (float)bh2[i];
    }
    v8h bl1 = pk8(r1), bl2 = pk8(r2);
    acc = MFMA(uf.h1, bl1, acc);
    acc = MFMA(uf.h2, bl2, acc);
    acc = MFMA(uf.l1, bh1, acc);
    acc = MFMA(uf.l2, bh2, acc);
  }
#pragma unroll
  for (int g = 0; g < 16; ++g) yio[g] = acc[g];
}

// M = logm(T X T^T) for one matrix, result in C-layout registers.
__device__ __forceinline__ void log_chain(const float* __restrict__ Xb, const Frag4& tf,
                                          const float (&dsel)[16], bool lower, int l,
                                          float (&Mc)[16])
{
  const int c = l & 31, k0 = 8 * (l >> 5);
  float a1[8], a2[8];
  {
    const float4 t0 = *(const float4*)(Xb + c * 32 + k0);
    const float4 t1 = *(const float4*)(Xb + c * 32 + k0 + 4);
    const float4 t2 = *(const float4*)(Xb + c * 32 + 16 + k0);
    const float4 t3 = *(const float4*)(Xb + c * 32 + 16 + k0 + 4);
    a1[0] = t0.x; a1[1] = t0.y; a1[2] = t0.z; a1[3] = t0.w;
    a1[4] = t1.x; a1[5] = t1.y; a1[6] = t1.z; a1[7] = t1.w;
    a2[0] = t2.x; a2[1] = t2.y; a2[2] = t2.z; a2[3] = t2.w;
    a2[4] = t3.x; a2[5] = t3.y; a2[6] = t3.z; a2[7] = t3.w;
  }
  Frag4 xf = split_frag(a1, a2);
  v16f acc;
#pragma unroll
  for (int g = 0; g < 16; ++g) acc[g] = 0.f;
  acc = prodAB(xf, tf, acc);              // H2 = X * T^T
  float h2[16];
#pragma unroll
  for (int g = 0; g < 16; ++g) h2[g] = acc[g];
  float v1[8], v2[8];
  gather16(h2, lower, v1, v2);
  Frag4 hf = split_frag(v1, v2);
  v16f wv;
#pragma unroll
  for (int g = 0; g < 16; ++g) wv[g] = 0.f;
  wv = prodAB(tf, hf, wv);                // W = T X T^T
  // U = (2/h) W - 2z I
  float Uc[16];
#pragma unroll
  for (int g = 0; g < 16; ++g) Uc[g] = fmaf(CH_2overH, (float)wv[g], -CH_2Z * dsel[g]);
  gather16(Uc, lower, v1, v2);            // A-frag(U), U sym
  Frag4 uf = split_frag(v1, v2);
  // y18 = c18 I ; y17 = c17 I + c18 U
  float ya[16], yb[16];
#pragma unroll
  for (int g = 0; g < 16; ++g) {
    ya[g] = fmaf(CH_C18, Uc[g], CH_C17 * dsel[g]);
    yb[g] = CH_C18 * dsel[g];
  }
  float pk = CH_PK16;
#pragma unroll 1
  for (int k = 16; k >= 2; k -= 2) {
    clen_step(ya, yb, -2.f * pk / (float)k, k <= KFULL, uf, dsel, lower);
    const float pk1 = pk * CH_TINV;
    clen_step(yb, ya, 2.f * pk1 / (float)(k - 1), (k - 1) <= KFULL, uf, dsel, lower);
    pk = pk1 * CH_TINV;
  }
  // f = c0 I + 0.5*U*y1 - y2   (y1 = ya, y2 = yb)
  gather16(ya, lower, v1, v2);
#pragma unroll
  for (int i = 0; i < 8; ++i) { v1[i] *= 0.5f; v2[i] *= 0.5f; }
  Frag4 yf = split_frag(v1, v2);
  v16f mv;
#pragma unroll
  for (int g = 0; g < 16; ++g) mv[g] = fmaf(CH_C0, dsel[g], -yb[g]);
  mv = prodAB(uf, yf, mv);
#pragma unroll
  for (int g = 0; g < 16; ++g) Mc[g] = mv[g];
}

// W = Lw * expm(Fc) * Lw^T (deg-7 Taylor; hi-only Horner steps k>=3).
__device__ __forceinline__ void exp_apply(const float (&Fc)[16], const Frag4& tw,
                                          const float (&dsel)[16], bool lower,
                                          float (&Wc)[16])
{
  float v1[8], v2[8];
  gather16(Fc, lower, v1, v2);
  Frag4 ff = split_frag(v1, v2);          // A-frag(F), F sym
  float s[16];
#pragma unroll
  for (int g = 0; g < 16; ++g) s[g] = fmaf(1.9841270e-4f, Fc[g], 1.3888889e-3f * dsel[g]);
  float ek = 8.3333333e-3f;               // 1/5!
#pragma unroll 1
  for (int k = 5; k >= 0; --k) {
    const bool full = (k <= 2);
    gather16(s, lower, v1, v2);
    v16f acc;
#pragma unroll
    for (int g = 0; g < 16; ++g) acc[g] = ek * dsel[g];
    v8h bh1 = cvt_hi(v1), bh2 = cvt_hi(v2);
    acc = MFMA(ff.h1, bh1, acc);
    acc = MFMA(ff.h2, bh2, acc);
    if (full) {
      float r1[8], r2[8];
#pragma unroll
      for (int i = 0; i < 8; ++i) {
        r1[i] = v1[i] - (float)bh1[i];
        r2[i] = v2[i] - (float)bh2[i];
      }
      v8h bl1 = pk8(r1), bl2 = pk8(r2);
      acc = MFMA(ff.h1, bl1, acc);
      acc = MFMA(ff.h2, bl2, acc);
      acc = MFMA(ff.l1, bh1, acc);
      acc = MFMA(ff.l2, bh2, acc);
    }
#pragma unroll
    for (int g = 0; g < 16; ++g) s[g] = acc[g];
    ek *= (float)k;
  }
  gather16(s, lower, v1, v2);             // A-frag(Xs), Xs sym
  Frag4 xf = split_frag(v1, v2);
  v16f h;
#pragma unroll
  for (int g = 0; g < 16; ++g) h[g] = 0.f;
  h = prodAB(xf, tw, h);                  // H2 = Xs * Lw^T
  float h2[16];
#pragma unroll
  for (int g = 0; g < 16; ++g) h2[g] = h[g];
  gather16(h2, lower, v1, v2);
  Frag4 hf = split_frag(v1, v2);
  v16f wv;
#pragma unroll
  for (int g = 0; g < 16; ++g) wv[g] = 0.f;
  wv = prodAB(tw, hf, wv);                // W = Lw * H2
#pragma unroll
  for (int g = 0; g < 16; ++g) Wc[g] = wv[g];
}

// ---------------------------------------------------------------------------
// VALU helpers for the tiny single-wave kernels.
__device__ __forceinline__ void mm_acc(const float* __restrict__ AT,
                                       const float* __restrict__ Bm,
                                       float (&acc)[4][4], int i0, int j0)
{
#pragma unroll
  for (int k = 0; k < NM; ++k) {
    const float4 a = *(const float4*)(AT + k * PAD + i0);
    const float4 b = *(const float4*)(Bm + k * PAD + j0);
    acc[0][0] = fmaf(a.x, b.x, acc[0][0]); acc[0][1] = fmaf(a.x, b.y, acc[0][1]);
    acc[0][2] = fmaf(a.x, b.z, acc[0][2]); acc[0][3] = fmaf(a.x, b.w, acc[0][3]);
    acc[1][0] = fmaf(a.y, b.x, acc[1][0]); acc[1][1] = fmaf(a.y, b.y, acc[1][1]);
    acc[1][2] = fmaf(a.y, b.z, acc[1][2]); acc[1][3] = fmaf(a.y, b.w, acc[1][3]);
    acc[2][0] = fmaf(a.z, b.x, acc[2][0]); acc[2][1] = fmaf(a.z, b.y, acc[2][1]);
    acc[2][2] = fmaf(a.z, b.z, acc[2][2]); acc[2][3] = fmaf(a.z, b.w, acc[2][3]);
    acc[3][0] = fmaf(a.w, b.x, acc[3][0]); acc[3][1] = fmaf(a.w, b.y, acc[3][1]);
    acc[3][2] = fmaf(a.w, b.z, acc[3][2]); acc[3][3] = fmaf(a.w, b.w, acc[3][3]);
  }
}

__device__ __forceinline__ void tile_store_sd(float* dst, const float (&acc)[4][4],
                                              int i0, int j0, float s, float dgv)
{
#pragma unroll
  for (int d = 0; d < 4; ++d) {
    float4 v;
    v.x = fmaf(acc[d][0], s, (i0 + d == j0 + 0) ? dgv : 0.f);
    v.y = fmaf(acc[d][1], s, (i0 + d == j0 + 1) ? dgv : 0.f);
    v.z = fmaf(acc[d][2], s, (i0 + d == j0 + 2) ? dgv : 0.f);
    v.w = fmaf(acc[d][3], s, (i0 + d == j0 + 3) ? dgv : 0.f);
    *(float4*)(dst + (i0 + d) * PAD + j0) = v;
  }
}

__device__ __forceinline__ void mm_store(const float* ATb, const float* Bb2, float* dst,
                                         float s, float dgv, int i0, int j0)
{
  float acc[4][4] = {};
  mm_acc(ATb, Bb2, acc, i0, j0);
  tile_store_sd(dst, acc, i0, j0, s, dgv);
}

// ---------------------------------------------------------------------------
// Register+shuffle Cholesky: lane j = l&31 owns column j in a[0..31]; on exit
// a[i] (i>=j) holds L[i][j].
__device__ __noinline__ void chol_reg(float (&a)[32], int j)
{
#pragma unroll
  for (int k = 0; k < 32; ++k) {
    const float dkk = __shfl(a[k], k);
    const float inv = 1.0f / sqrtf(dkk);
    float Lk[32];
    float ljk = 0.f;
#pragma unroll
    for (int i = k; i < 32; ++i) {
      Lk[i] = __shfl(a[i], k) * inv;
      if (i == j) ljk = Lk[i];          // j < k never selects -> ljk stays 0
    }
#pragma unroll
    for (int i = k; i < 32; ++i)
      a[i] = (j == k) ? Lk[i] : fmaf(-Lk[i], ljk, a[i]);
  }
}

// Column j of L^{-1} by forward substitution (column sweep), result in x.
__device__ __noinline__ void trinv_reg(const float (&a)[32], int j, float (&x)[32])
{
#pragma unroll
  for (int i = 0; i < 32; ++i) x[i] = (i == j) ? 1.f : 0.f;
#pragma unroll
  for (int kk = 0; kk < 32; ++kk) {
    const float d = __shfl(a[kk], kk);
    const float xk = x[kk] / d;
    x[kk] = xk;
#pragma unroll
    for (int i = kk + 1; i < 32; ++i)
      x[i] = fmaf(-__shfl(a[i], kk), xk, x[i]);
  }
}

// ---------------------------------------------------------------------------
// P0: bm accumulation
__global__ __launch_bounds__(256) void k_bmsum(const float* __restrict__ X,
                                               float* __restrict__ bm_acc, int mats)
{
  const int t = threadIdx.x;
  const float* base = X + (size_t)blockIdx.x * mats * (NM * NM);
  float s0 = 0.f, s1 = 0.f, s2 = 0.f, s3 = 0.f;
  for (int b = 0; b < mats; ++b) {
    const float* Xb = base + (size_t)b * (NM * NM);
    s0 += Xb[t]; s1 += Xb[t + 256]; s2 += Xb[t + 512]; s3 += Xb[t + 768];
  }
  atomicAdd(&bm_acc[t], s0);       atomicAdd(&bm_acc[t + 256], s1);
  atomicAdd(&bm_acc[t + 512], s2); atomicAdd(&bm_acc[t + 768], s3);
}

// P0b: bm^{1/2}, bm^{-1/2} via Taylor of (I+E)^{-1/2}, E = bm/2 - I
__global__ void k_bmroot(const float* __restrict__ bm_acc, float inv_batch,
                         float* __restrict__ bm_sq_out, float* __restrict__ bm_isq_out)
{
  __shared__ float sBM[NM * PAD], U[NM * PAD], bA[NM * PAD], bB[NM * PAD];
  __shared__ float sBC[EXP_DEG + 1];
  const int l = threadIdx.x;
  const int i0 = ((l >> 3) & 7) * 4, j0 = (l & 7) * 4;
  for (int e = l; e < NM * NM; e += 64) {
    const int ei = e >> 5, ej = e & 31;
    const float v = bm_acc[e] * inv_batch;
    sBM[ei * PAD + ej] = v;
    U[ei * PAD + ej] = 0.5f * v - ((ei == ej) ? 1.f : 0.f);
  }
  if (l == 0) {
    float bcv = 1.f; sBC[0] = 1.f;
    for (int k = 1; k <= EXP_DEG; ++k) { bcv *= (-0.5f - (float)(k - 1)) / (float)k; sBC[k] = bcv; }
  }
  __syncthreads();
#pragma unroll
  for (int d = 0; d < 4; ++d) {
    const float4 u4 = *(const float4*)(U + (i0 + d) * PAD + j0);
    float4 v;
    v.x = fmaf(sBC[EXP_DEG], u4.x, (i0 + d == j0 + 0) ? sBC[EXP_DEG - 1] : 0.f);
    v.y = fmaf(sBC[EXP_DEG], u4.y, (i0 + d == j0 + 1) ? sBC[EXP_DEG - 1] : 0.f);
    v.z = fmaf(sBC[EXP_DEG], u4.z, (i0 + d == j0 + 2) ? sBC[EXP_DEG - 1] : 0.f);
    v.w = fmaf(sBC[EXP_DEG], u4.w, (i0 + d == j0 + 3) ? sBC[EXP_DEG - 1] : 0.f);
    *(float4*)(bB + (i0 + d) * PAD + j0) = v;
  }
  float* y1 = bB; float* y2 = bA;
#pragma unroll 1
  for (int k = EXP_DEG - 2; k >= 0; --k) {
    float acc[4][4] = {};
    mm_acc(U, y1, acc, i0, j0);
    tile_store_sd(y2, acc, i0, j0, 1.f, sBC[k]);
    float* tp = y1; y1 = y2; y2 = tp;
  }
  const float is2 = 0.70710678118f;
#pragma unroll
  for (int d = 0; d < 4; ++d) {
    const float4 s4 = *(const float4*)(y1 + (i0 + d) * PAD + j0);
    *(float4*)(bm_isq_out + (i0 + d) * NM + j0) =
        make_float4(s4.x * is2, s4.y * is2, s4.z * is2, s4.w * is2);
  }
  float acc[4][4] = {};
  mm_acc(sBM, y1, acc, i0, j0);
#pragma unroll
  for (int d = 0; d < 4; ++d)
    *(float4*)(bm_sq_out + (i0 + d) * NM + j0) =
        make_float4(acc[d][0] * is2, acc[d][1] * is2, acc[d][2] * is2, acc[d][3] * is2);
}

// P1: GT accumulation (MFMA chains) — A-arm: launch_bounds (256,3)
__global__ __launch_bounds__(256, 3) void k_karcher(const float* __restrict__ X,
                                                    const float* __restrict__ Sm,
                                                    float* __restrict__ gt_acc)
{
  __shared__ float red[WCNT][NM * PAD];
  const int tid = threadIdx.x, w = tid >> 6, l = tid & 63;
  const bool lower = l < 32;
  const int c = l & 31, rb = 4 * (l >> 5);
  float dsel[16];
#pragma unroll
  for (int g = 0; g < 16; ++g) dsel[g] = ((g & 3) + 8 * (g >> 2) + rb == c) ? 1.f : 0.f;
  Frag4 tf = load_T(Sm, l);
  float gt[16];
#pragma unroll
  for (int g = 0; g < 16; ++g) gt[g] = 0.f;
#pragma unroll 1
  for (int it = 0; it < ITER; ++it) {
    const int b = (blockIdx.x * WCNT + w) * ITER + it;
    float Mc[16];
    log_chain(X + (size_t)b * (NM * NM), tf, dsel, lower, l, Mc);
#pragma unroll
    for (int g = 0; g < 16; ++g) gt[g] += Mc[g];
  }
#pragma unroll
  for (int q = 0; q < 4; ++q)
    *(float4*)(&red[w][c * PAD + 8 * q + rb]) =
        make_float4(gt[4 * q], gt[4 * q + 1], gt[4 * q + 2], gt[4 * q + 3]);
  __syncthreads();
  for (int e = tid; e < NM * NM; e += 256) {
    const int i = e >> 5, j = e & 31;
    float s = 0.f;
#pragma unroll
    for (int ww = 0; ww < WCNT; ++ww) s += red[ww][j * PAD + i];
    atomicAdd(&gt_acc[e], s);
  }
}

// P2: batch_mean = bm_sq expm(GT) bm_sq; Linv, Lw via register-shuffle chol
__global__ void k_prep(const float* __restrict__ gt_acc, float inv_batch,
                       const float* __restrict__ bm_sq_g, const float* __restrict__ weight,
                       float* __restrict__ Linv_out, float* __restrict__ Lw_out)
{
  __shared__ float sS[NM * PAD], U[NM * PAD], bA[NM * PAD], bB[NM * PAD];
  __shared__ float sEC[EXP_DEG + 1];
  const int l = threadIdx.x;
  const int i0 = ((l >> 3) & 7) * 4, j0 = (l & 7) * 4;
  for (int e = l; e < NM * NM; e += 64) {
    const int ei = e >> 5, ej = e & 31;
    sS[ei * PAD + ej] = bm_sq_g[e];
    U[ei * PAD + ej] = gt_acc[e] * inv_batch;
  }
  if (l == 0) {
    float fc = 1.f; sEC[0] = 1.f;
    for (int k = 1; k <= EXP_DEG; ++k) { fc /= (float)k; sEC[k] = fc; }
  }
  __syncthreads();
#pragma unroll
  for (int d = 0; d < 4; ++d) {
    const float4 u4 = *(const float4*)(U + (i0 + d) * PAD + j0);
    float4 v;
    v.x = fmaf(sEC[EXP_DEG], u4.x, (i0 + d == j0 + 0) ? sEC[EXP_DEG - 1] : 0.f);
    v.y = fmaf(sEC[EXP_DEG], u4.y, (i0 + d == j0 + 1) ? sEC[EXP_DEG - 1] : 0.f);
    v.z = fmaf(sEC[EXP_DEG], u4.z, (i0 + d == j0 + 2) ? sEC[EXP_DEG - 1] : 0.f);
    v.w = fmaf(sEC[EXP_DEG], u4.w, (i0 + d == j0 + 3) ? sEC[EXP_DEG - 1] : 0.f);
    *(float4*)(bB + (i0 + d) * PAD + j0) = v;
  }
  float* y1 = bB; float* y2 = bA;
#pragma unroll 1
  for (int k = EXP_DEG - 2; k >= 0; --k) {
    float acc[4][4] = {};
    mm_acc(U, y1, acc, i0, j0);
    tile_store_sd(y2, acc, i0, j0, 1.f, sEC[k]);
    float* tp = y1; y1 = y2; y2 = tp;
  }
  mm_store(y1, sS, y2, 1.f, 0.f, i0, j0);   // expG * bm_sq
  mm_store(sS, y2, U, 1.f, 0.f, i0, j0);    // batch_mean -> U
  __syncthreads();
  const int j = l & 31;
  float a[32];
#pragma unroll
  for (int i = 0; i < 32; ++i) a[i] = U[i * PAD + j];
  chol_reg(a, j);
  float x[32];
  trinv_reg(a, j, x);
  if (l < 32) {
#pragma unroll
    for (int i = 0; i < 32; ++i) Linv_out[i * 32 + j] = x[i];
  }
  float b[32];
#pragma unroll
  for (int i = 0; i < 32; ++i) b[i] = weight[i * 32 + j];
  chol_reg(b, j);
  if (l < 32) {
#pragma unroll
    for (int i = 0; i < 32; ++i) Lw_out[i * 32 + j] = (i >= j) ? b[i] : 0.f;
  }
}

// P3: M = logm(Linv X Linv^T); var += ||M||_F^2 — B-arm: launch_bounds (256,4)
__global__ __launch_bounds__(256, 4) void k_center(const float* __restrict__ X,
                                                   const float* __restrict__ Linv,
                                                   float* __restrict__ Mout,
                                                   float* __restrict__ var_acc, int storeM)
{
  const int tid = threadIdx.x, w = tid >> 6, l = tid & 63;
  const bool lower = l < 32;
  const int c = l & 31, rb = 4 * (l >> 5);
  float dsel[16];
#pragma unroll
  for (int g = 0; g < 16; ++g) dsel[g] = ((g & 3) + 8 * (g >> 2) + rb == c) ? 1.f : 0.f;
  Frag4 tf = load_T(Linv, l);
  float dist = 0.f;
#pragma unroll 1
  for (int it = 0; it < ITER; ++it) {
    const int b = (blockIdx.x * WCNT + w) * ITER + it;
    float Mc[16];
    log_chain(X + (size_t)b * (NM * NM), tf, dsel, lower, l, Mc);
    if (storeM) {
      float* Mb = Mout + (size_t)b * (NM * NM) + l * 16;
#pragma unroll
      for (int q = 0; q < 4; ++q)
        *(float4*)(Mb + 4 * q) =
            make_float4(Mc[4 * q], Mc[4 * q + 1], Mc[4 * q + 2], Mc[4 * q + 3]);
    }
#pragma unroll
    for (int g = 0; g < 16; ++g) dist = fmaf(Mc[g], Mc[g], dist);
  }
  for (int off = 32; off > 0; off >>= 1) dist += __shfl_down(dist, off);
  if (l == 0) atomicAdd(var_acc, dist);
}

// P4: out = Lw expm(f*M) Lw^T (M from ws, frag order)
__global__ __launch_bounds__(256, 4) void k_scale(const float* __restrict__ Mi,
                                                  const float* __restrict__ Lw,
                                                  const float* __restrict__ shift,
                                                  const float* __restrict__ var_acc,
                                                  float* __restrict__ out, float invb)
{
  const int tid = threadIdx.x, w = tid >> 6, l = tid & 63;
  const bool lower = l < 32;
  const int c = l & 31, rb = 4 * (l >> 5);
  float dsel[16];
#pragma unroll
  for (int g = 0; g < 16; ++g) dsel[g] = ((g & 3) + 8 * (g >> 2) + rb == c) ? 1.f : 0.f;
  Frag4 tw = load_T(Lw, l);
  const float fac = shift[0] / sqrtf(var_acc[0] * invb + 1e-5f);
#pragma unroll 1
  for (int it = 0; it < ITER; ++it) {
    const int b = (blockIdx.x * WCNT + w) * ITER + it;
    const float* Mb = Mi + (size_t)b * (NM * NM) + l * 16;
    float Fc[16];
#pragma unroll
    for (int q = 0; q < 4; ++q) {
      const float4 m4 = *(const float4*)(Mb + 4 * q);
      Fc[4 * q] = fac * m4.x; Fc[4 * q + 1] = fac * m4.y;
      Fc[4 * q + 2] = fac * m4.z; Fc[4 * q + 3] = fac * m4.w;
    }
    float Wc[16];
    exp_apply(Fc, tw, dsel, lower, Wc);
    float* ob = out + (size_t)b * (NM * NM);
#pragma unroll
    for (int q = 0; q < 4; ++q)
      *(float4*)(ob + c * 32 + 8 * q + rb) =
          make_float4(Wc[4 * q], Wc[4 * q + 1], Wc[4 * q + 2], Wc[4 * q + 3]);
  }
}

// P4b fallback (ws too small): recompute log, then exp + output
__global__ __launch_bounds__(256, 3) void k_scale2(const float* __restrict__ X,
                                                   const float* __restrict__ Linv,
                                                   const float* __restrict__ Lw,
                                                   const float* __restrict__ shift,
                                                   const float* __restrict__ var_acc,
                                                   float* __restrict__ out, float invb)
{
  const int tid = threadIdx.x, w = tid >> 6, l = tid & 63;
  const bool lower = l < 32;
  const int c = l & 31, rb = 4 * (l >> 5);
  float dsel[16];
#pragma unroll
  for (int g = 0; g < 16; ++g) dsel[g] = ((g & 3) + 8 * (g >> 2) + rb == c) ? 1.f : 0.f;
  Frag4 tf = load_T(Linv, l);
  Frag4 tw = load_T(Lw, l);
  const float fac = shift[0] / sqrtf(var_acc[0] * invb + 1e-5f);
#pragma unroll 1
  for (int it = 0; it < ITER; ++it) {
    const int b = (blockIdx.x * WCNT + w) * ITER + it;
    float Mc[16];
    log_chain(X + (size_t)b * (NM * NM), tf, dsel, lower, l, Mc);
#pragma unroll
    for (int g = 0; g < 16; ++g) Mc[g] *= fac;
    float Wc[16];
    exp_apply(Mc, tw, dsel, lower, Wc);
    float* ob = out + (size_t)b * (NM * NM);
#pragma unroll
    for (int q = 0; q < 4; ++q)
      *(float4*)(ob + c * 32 + 8 * q + rb) =
          make_float4(Wc[4 * q], Wc[4 * q + 1], Wc[4 * q + 2], Wc[4 * q + 3]);
  }
}

// ---------------------------------------------------------------------------
extern "C" void kernel_launch(void* const* d_in, const int* in_sizes, int n_in,
                              void* d_out, int out_size, void* d_ws, size_t ws_size,
                              hipStream_t stream)
{
  const float* X = (const float*)d_in[0];
  const float* weight = (const float*)d_in[1];
  const float* shift = (const float*)d_in[2];
  float* out = (float*)d_out;
  float* W = (float*)d_ws;
  const int batch = in_sizes[0] / (NM * NM);          // 16384
  float* bm_acc = W;                                  // 1024
  float* gt_acc = W + 1024;                           // 1024
  float* var_acc = W + 2048;                          // 1 (+pad)
  float* bm_sq = W + 2304;                            // 1024
  float* bm_isq = W + 3328;                           // 1024
  float* Linv = W + 4352;                             // 1024 (row-major)
  float* Lw = W + 5376;                               // 1024 (row-major)
  float* M = W + 6400;                                // batch*1024
  const size_t needM = (size_t)(6400 + (size_t)batch * NM * NM) * sizeof(float);
  const int storeM = (ws_size >= needM) ? 1 : 0;
  const int GS = 512;                                 // bmsum grid
  const int GB = batch / (WCNT * ITER);               // 1024 blocks, 16 matrices each
  const float invb = 1.f / (float)batch;

  (void)hipMemsetAsync(W, 0, 2056 * sizeof(float), stream);

  hipLaunchKernelGGL(k_bmsum, dim3(GS), dim3(256), 0, stream, X, bm_acc, batch / GS);
  hipLaunchKernelGGL(k_bmroot, dim3(1), dim3(64), 0, stream, bm_acc, invb, bm_sq, bm_isq);
  hipLaunchKernelGGL(k_karcher, dim3(GB), dim3(256), 0, stream, X, bm_isq, gt_acc);
  hipLaunchKernelGGL(k_prep, dim3(1), dim3(64), 0, stream, gt_acc, invb, bm_sq, weight, Linv, Lw);
  hipLaunchKernelGGL(k_center, dim3(GB), dim3(256), 0, stream, X, Linv, M, var_acc, storeM);
  if (storeM)
    hipLaunchKernelGGL(k_scale, dim3(GB), dim3(256), 0, stream, M, Lw, shift, var_acc, out, invb);
  else
    hipLaunchKernelGGL(k_scale2, dim3(GB), dim3(256), 0, stream, X, Linv, Lw, shift, var_acc, out, invb);
}